// Round 5
// baseline (465.085 us; speedup 1.0000x reference)
//
#include <hip/hip_runtime.h>
#include <math.h>

#define N_SAMP   32768
#define WINDOW   512
#define STEP     256
#define NFRAMES  127      // (32768-512)/256 + 1
#define NB       4

// ws layout (float granularity)
#define WS_WF   0               // 4*127*512 = 260096 floats
#define WS_PV   260096          // 4064 floats  (partial max values)
#define WS_PI   264160          // 4064 ints    (partial max indices)
#define WS_M    268224          // 508 ints     (argmax per (b,f))
#define WS_PART 268736          // nfg*4*32768 floats (per-fg partials)

// XOR swizzle on float4-block index: makes lane-stride-4-block reads an
// 8-phase permutation (same LDS cost as contiguous b128).
#define SW(L) ((L) ^ (((L) >> 3) & 7))

// 16 fma for 4 outputs: c = wf[4g..4g+3], HI = h[base..base+3], LO = h[base-4..base-1]
#define FMA4(A, LO, HI)                                           \
    A.x = fmaf(c.x, HI.x, A.x); A.x = fmaf(c.y, LO.w, A.x);       \
    A.x = fmaf(c.z, LO.z, A.x); A.x = fmaf(c.w, LO.y, A.x);       \
    A.y = fmaf(c.x, HI.y, A.y); A.y = fmaf(c.y, HI.x, A.y);       \
    A.y = fmaf(c.z, LO.w, A.y); A.y = fmaf(c.w, LO.z, A.y);       \
    A.z = fmaf(c.x, HI.z, A.z); A.z = fmaf(c.y, HI.y, A.z);       \
    A.z = fmaf(c.z, HI.x, A.z); A.z = fmaf(c.w, LO.w, A.z);       \
    A.w = fmaf(c.x, HI.w, A.w); A.w = fmaf(c.y, HI.z, A.w);       \
    A.w = fmaf(c.z, HI.y, A.w); A.w = fmaf(c.w, HI.x, A.w);

#define LDBLK(SH, n) (*(const float4*)((SH) + 4 * SW(Lb + (n))))

#define CBODY(SH, g, S0, S1, S2, S3, S4)                          \
    {                                                             \
        float4 tnew = LDBLK(SH, 127 - (g) - 1);                   \
        const float4 c = wc[(g)];                                 \
        FMA4(acc0, w[S0], w[S1]); FMA4(acc1, w[S1], w[S2]);       \
        FMA4(acc2, w[S2], w[S3]); FMA4(acc3, w[S3], w[S4]);       \
        w[S4] = tnew;                                             \
    }
#define CBODY_NL(g, S0, S1, S2, S3, S4)                           \
    {                                                             \
        const float4 c = wc[(g)];                                 \
        FMA4(acc0, w[S0], w[S1]); FMA4(acc1, w[S1], w[S2]);       \
        FMA4(acc2, w[S2], w[S3]); FMA4(acc3, w[S3], w[S4]);       \
    }

#define CONV512(SH)                                               \
    {                                                             \
        float4 w[5];                                              \
        w[2] = LDBLK(SH, 127); w[3] = LDBLK(SH, 128);             \
        w[4] = LDBLK(SH, 129); w[0] = LDBLK(SH, 130);             \
        w[1] = LDBLK(SH, 131);                                    \
        for (int go = 0; go < 25; ++go) {                         \
            const int gb = 5 * go;                                \
            CBODY(SH, gb + 0, 2, 3, 4, 0, 1);                     \
            CBODY(SH, gb + 1, 1, 2, 3, 4, 0);                     \
            CBODY(SH, gb + 2, 0, 1, 2, 3, 4);                     \
            CBODY(SH, gb + 3, 4, 0, 1, 2, 3);                     \
            CBODY(SH, gb + 4, 3, 4, 0, 1, 2);                     \
        }                                                         \
        CBODY(SH, 125, 2, 3, 4, 0, 1);                            \
        CBODY(SH, 126, 1, 2, 3, 4, 0);                            \
        CBODY_NL(   127, 0, 1, 2, 3, 4);                          \
    }

// ---------------------------------------------------------------- kernel A
__global__ __launch_bounds__(256) void k_wf(const float* __restrict__ recon,
                                            float* __restrict__ wf) {
    int e = blockIdx.x * 256 + threadIdx.x;
    if (e >= NB * NFRAMES * WINDOW) return;
    int w  = e & 511;
    int bf = e >> 9;
    int f  = bf % NFRAMES;
    int b  = bf / NFRAMES;
    float ham = 0.54f - 0.46f * (float)cos((double)w * (M_PI / 256.0));
    wf[e] = ham * recon[b * N_SAMP + f * STEP + w];
}

// ---------------------------------------------------------------- kernel B
// LDS = 4608 floats = 18432 B -> 8 blocks/CU (32-wave cap). rv/ri reuse s_tg.
__global__ __launch_bounds__(256, 8) void k_argmax(const float* __restrict__ tgt,
                                                   const float* __restrict__ wf,
                                                   float* __restrict__ pv,
                                                   int*   __restrict__ pi) {
    __shared__ __align__(16) float s_tg[4608];   // blocks [t0-512, t0+4096)
    const int tid  = threadIdx.x;
    const int tile = blockIdx.x & 7;
    const int bf   = blockIdx.x >> 3;
    const int b    = bf / NFRAMES;
    const float* tb = tgt + b * N_SAMP;
    const float4* __restrict__ wc = (const float4*)(wf + bf * 512);
    const int t0 = tile * 4096;
    const int Lb = 4 * tid;

    for (int e4 = tid; e4 < 1152; e4 += 256) {
        int g = t0 - 512 + 4 * e4;
        float4 v;
        if (g >= 0) v = *(const float4*)(tb + g);
        else        v = make_float4(0.f, 0.f, 0.f, 0.f);
        *(float4*)(s_tg + 4 * SW(e4)) = v;
    }
    __syncthreads();

    float4 acc0 = make_float4(0.f, 0.f, 0.f, 0.f);
    float4 acc1 = acc0, acc2 = acc0, acc3 = acc0;
    CONV512(s_tg)

    float best = -3.4e38f;
    int   bidx = 0;
    const int tbase = t0 + 16 * tid;
#define AMX(v, i) if ((v) > best) { best = (v); bidx = (i); }
    AMX(acc0.x, tbase + 0)  AMX(acc0.y, tbase + 1)
    AMX(acc0.z, tbase + 2)  AMX(acc0.w, tbase + 3)
    AMX(acc1.x, tbase + 4)  AMX(acc1.y, tbase + 5)
    AMX(acc1.z, tbase + 6)  AMX(acc1.w, tbase + 7)
    AMX(acc2.x, tbase + 8)  AMX(acc2.y, tbase + 9)
    AMX(acc2.z, tbase + 10) AMX(acc2.w, tbase + 11)
    AMX(acc3.x, tbase + 12) AMX(acc3.y, tbase + 13)
    AMX(acc3.z, tbase + 14) AMX(acc3.w, tbase + 15)
#undef AMX

    float* rv = s_tg;                 // reuse conv buffer for reduction
    int*   ri = (int*)(s_tg + 256);
    __syncthreads();                  // all conv reads of s_tg done
    rv[tid] = best; ri[tid] = bidx;
    __syncthreads();
    for (int s = 128; s > 0; s >>= 1) {
        if (tid < s) {
            float v2 = rv[tid + s]; int i2 = ri[tid + s];
            if (v2 > rv[tid] || (v2 == rv[tid] && i2 < ri[tid])) {
                rv[tid] = v2; ri[tid] = i2;
            }
        }
        __syncthreads();
    }
    if (tid == 0) { pv[blockIdx.x] = rv[0]; pi[blockIdx.x] = ri[0]; }
}

// ---------------------------------------------------------------- kernel C
__global__ __launch_bounds__(256) void k_reduce(const float* __restrict__ pv,
                                                const int* __restrict__ pi,
                                                int* __restrict__ marr) {
    int id = blockIdx.x * 256 + threadIdx.x;
    if (id >= NB * NFRAMES) return;
    float best = -3.4e38f; int bidx = 0x7fffffff;
    for (int t = 0; t < 8; ++t) {
        float v = pv[id * 8 + t]; int i = pi[id * 8 + t];
        if (v > best || (v == best && i < bidx)) { best = v; bidx = i; }
    }
    marr[id] = bidx;
}

// ---------------------------------------------------------------- kernel D
// h[j] = (-1)^(j+m) * (sin(pi*m/32769)/65536) * cot(pi*frac(A_j/D))
//   A_j = j*32769 - m*32768, D = 65536*32769; m==0 -> delta at j=0.
__global__ __launch_bounds__(256, 8) void k_shift_acc(const float* __restrict__ wf,
                                                      const int* __restrict__ marr,
                                                      float* __restrict__ part,
                                                      int nfgm1, int lg, int fpg) {
    __shared__ __align__(16) float s_h[4608];    // blocks [t0-512, t0+4096)
    const int tid   = threadIdx.x;
    const int cid   = blockIdx.x;
    const int fg    = cid & nfgm1;
    const int chunk = (cid >> lg) & 7;
    const int b     = cid >> (lg + 3);
    const int t0    = chunk * 4096;
    const int f0    = fg * fpg;
    const int nf    = (f0 + fpg <= NFRAMES) ? fpg : (NFRAMES - f0);
    const int Lb    = 4 * tid;

    float4 acc0 = make_float4(0.f, 0.f, 0.f, 0.f);
    float4 acc1 = acc0, acc2 = acc0, acc3 = acc0;
    const double invD = 1.0 / 2147549184.0;   // 1/(65536*32769)

    for (int u = 0; u < nf; ++u) {
        int bf = b * NFRAMES + f0 + u;
        const float4* __restrict__ wc = (const float4*)(wf + bf * 512);

        int m = marr[bf];
        double md32768 = (double)m * 32768.0;
        double sp = sin((double)m * (M_PI / 32769.0));
        float Cp = (float)(sp * (1.0 / 65536.0));
        if (m & 1) Cp = -Cp;
        float Cn = -Cp;    // odd-j elements

        __syncthreads();   // previous frame's conv reads done before re-staging
        if (m == 0) {
            for (int e4 = tid; e4 < 1152; e4 += 256) {
                int j0 = t0 - 512 + 4 * e4;
                float4 v;
                v.x = (j0 == 0) ? 1.0f : 0.0f;
                v.y = 0.0f; v.z = 0.0f; v.w = 0.0f;
                *(float4*)(s_h + 4 * SW(e4)) = v;
            }
        } else {
            for (int e4 = tid; e4 < 1152; e4 += 256) {
                int j0 = t0 - 512 + 4 * e4;         // always even
                double A0 = (double)j0 * 32769.0 - md32768;   // exact integer
                float4 v;
#pragma unroll
                for (int k = 0; k < 4; ++k) {
                    double rA = (A0 + (double)k * 32769.0) * invD;
                    float f = (float)(rA - rint(rA));
                    float s, c;
                    __sincosf((float)M_PI * f, &s, &c);
                    float r = c * __builtin_amdgcn_rcpf(s);
                    ((float*)&v)[k] = ((k & 1) ? Cn : Cp) * r;
                }
                *(float4*)(s_h + 4 * SW(e4)) = v;
            }
        }
        __syncthreads();

        CONV512(s_h)
    }

    float* ob = part + (size_t)fg * (NB * N_SAMP) + b * N_SAMP + t0 + 16 * tid;
    *(float4*)(ob + 0)  = acc0;
    *(float4*)(ob + 4)  = acc1;
    *(float4*)(ob + 8)  = acc2;
    *(float4*)(ob + 12) = acc3;
}

// ---------------------------------------------------------------- kernel E
__global__ __launch_bounds__(256) void k_mse(const float* __restrict__ part,
                                             const float* __restrict__ tgt,
                                             float* __restrict__ out, int nfg) {
    __shared__ float sred[4];
    int e = blockIdx.x * 256 + threadIdx.x;
    float s0 = 0.f, s1 = 0.f, s2 = 0.f, s3 = 0.f;
    for (int g = 0; g + 4 <= nfg; g += 4) {
        s0 += part[(size_t)(g + 0) * (NB * N_SAMP) + e];
        s1 += part[(size_t)(g + 1) * (NB * N_SAMP) + e];
        s2 += part[(size_t)(g + 2) * (NB * N_SAMP) + e];
        s3 += part[(size_t)(g + 3) * (NB * N_SAMP) + e];
    }
    float s = (s0 + s1) + (s2 + s3);
    float d = s - tgt[e];
    float v = d * d;
#pragma unroll
    for (int off = 32; off > 0; off >>= 1) v += __shfl_down(v, off, 64);
    int lane = threadIdx.x & 63, wid = threadIdx.x >> 6;
    if (lane == 0) sred[wid] = v;
    __syncthreads();
    if (threadIdx.x == 0) {
        float sm = sred[0] + sred[1] + sred[2] + sred[3];
        atomicAdd(out, sm * (1.0f / 131072.0f));
    }
}

// ---------------------------------------------------------------- launch
extern "C" void kernel_launch(void* const* d_in, const int* in_sizes, int n_in,
                              void* d_out, int out_size, void* d_ws, size_t ws_size,
                              hipStream_t stream) {
    const float* recon = (const float*)d_in[0];
    const float* tgt   = (const float*)d_in[1];
    float* out = (float*)d_out;
    float* W   = (float*)d_ws;

    float* wf   = W + WS_WF;
    float* pv   = W + WS_PV;
    int*   pi   = (int*)(W + WS_PI);
    int*   marr = (int*)(W + WS_M);
    float* part = W + WS_PART;

    // 64 frame-groups (2 frames each) -> grid 2048 = exactly 8 blocks/CU.
    // Fallback to 16 groups if workspace can't hold 64 partial slabs.
    int nfg = 64, lg = 6, fpg = 2;
    size_t need = ((size_t)WS_PART + (size_t)nfg * NB * N_SAMP) * sizeof(float);
    if (ws_size < need) { nfg = 16; lg = 4; fpg = 8; }

    hipMemsetAsync(out, 0, sizeof(float), stream);

    k_wf<<<(NB * NFRAMES * WINDOW + 255) / 256, 256, 0, stream>>>(recon, wf);
    k_argmax<<<NB * NFRAMES * 8, 256, 0, stream>>>(tgt, wf, pv, pi);
    k_reduce<<<2, 256, 0, stream>>>(pv, pi, marr);
    k_shift_acc<<<NB * 8 * nfg, 256, 0, stream>>>(wf, marr, part, nfg - 1, lg, fpg);
    k_mse<<<512, 256, 0, stream>>>(part, tgt, out, nfg);
}

// Round 6
// 456.927 us; speedup vs baseline: 1.0179x; 1.0179x over previous
//
#include <hip/hip_runtime.h>
#include <math.h>

#define N_SAMP   32768
#define WINDOW   512
#define STEP     256
#define NFRAMES  127      // (32768-512)/256 + 1
#define NB       4

// ws layout (float granularity)
#define WS_WF   0               // 4*127*512 = 260096 floats
#define WS_PV   260096          // 4064 floats  (partial max values)
#define WS_PI   264160          // 4064 ints    (partial max indices)
#define WS_M    268224          // 508 ints     (argmax per (b,f))
#define WS_PART 268736          // nfg*4*32768 floats (per-fg partials)

// XOR swizzle on float4-block index: makes lane-stride-4-block reads an
// 8-phase permutation (same LDS cost as contiguous b128).
#define SW(L) ((L) ^ (((L) >> 3) & 7))

// 16 fma for 4 outputs: c = wf[4g..4g+3], HI = h[base..base+3], LO = h[base-4..base-1]
#define FMA4(A, LO, HI)                                           \
    A.x = fmaf(c.x, HI.x, A.x); A.x = fmaf(c.y, LO.w, A.x);       \
    A.x = fmaf(c.z, LO.z, A.x); A.x = fmaf(c.w, LO.y, A.x);       \
    A.y = fmaf(c.x, HI.y, A.y); A.y = fmaf(c.y, HI.x, A.y);       \
    A.y = fmaf(c.z, LO.w, A.y); A.y = fmaf(c.w, LO.z, A.y);       \
    A.z = fmaf(c.x, HI.z, A.z); A.z = fmaf(c.y, HI.y, A.z);       \
    A.z = fmaf(c.z, HI.x, A.z); A.z = fmaf(c.w, LO.w, A.z);       \
    A.w = fmaf(c.x, HI.w, A.w); A.w = fmaf(c.y, HI.z, A.w);       \
    A.w = fmaf(c.z, HI.y, A.w); A.w = fmaf(c.w, HI.x, A.w);

#define LDBLK(SH, n) (*(const float4*)((SH) + 4 * SW(Lb + (n))))

#define CBODY(SH, g, S0, S1, S2, S3, S4)                          \
    {                                                             \
        float4 tnew = LDBLK(SH, 127 - (g) - 1);                   \
        const float4 c = wc[(g)];                                 \
        FMA4(acc0, w[S0], w[S1]); FMA4(acc1, w[S1], w[S2]);       \
        FMA4(acc2, w[S2], w[S3]); FMA4(acc3, w[S3], w[S4]);       \
        w[S4] = tnew;                                             \
    }
#define CBODY_NL(g, S0, S1, S2, S3, S4)                           \
    {                                                             \
        const float4 c = wc[(g)];                                 \
        FMA4(acc0, w[S0], w[S1]); FMA4(acc1, w[S1], w[S2]);       \
        FMA4(acc2, w[S2], w[S3]); FMA4(acc3, w[S3], w[S4]);       \
    }

#define CONV512(SH)                                               \
    {                                                             \
        float4 w[5];                                              \
        w[2] = LDBLK(SH, 127); w[3] = LDBLK(SH, 128);             \
        w[4] = LDBLK(SH, 129); w[0] = LDBLK(SH, 130);             \
        w[1] = LDBLK(SH, 131);                                    \
        for (int go = 0; go < 25; ++go) {                         \
            const int gb = 5 * go;                                \
            CBODY(SH, gb + 0, 2, 3, 4, 0, 1);                     \
            CBODY(SH, gb + 1, 1, 2, 3, 4, 0);                     \
            CBODY(SH, gb + 2, 0, 1, 2, 3, 4);                     \
            CBODY(SH, gb + 3, 4, 0, 1, 2, 3);                     \
            CBODY(SH, gb + 4, 3, 4, 0, 1, 2);                     \
        }                                                         \
        CBODY(SH, 125, 2, 3, 4, 0, 1);                            \
        CBODY(SH, 126, 1, 2, 3, 4, 0);                            \
        CBODY_NL(   127, 0, 1, 2, 3, 4);                          \
    }

// ---------------------------------------------------------------- kernel A
__global__ __launch_bounds__(256) void k_wf(const float* __restrict__ recon,
                                            float* __restrict__ wf) {
    int e = blockIdx.x * 256 + threadIdx.x;
    if (e >= NB * NFRAMES * WINDOW) return;
    int w  = e & 511;
    int bf = e >> 9;
    int f  = bf % NFRAMES;
    int b  = bf / NFRAMES;
    float ham = 0.54f - 0.46f * (float)cos((double)w * (M_PI / 256.0));
    wf[e] = ham * recon[b * N_SAMP + f * STEP + w];
}

// ---------------------------------------------------------------- kernel B
// LDS = 4608 floats = 18432 B -> 8 blocks/CU (32-wave cap). rv/ri reuse s_tg.
__global__ __launch_bounds__(256, 8) void k_argmax(const float* __restrict__ tgt,
                                                   const float* __restrict__ wf,
                                                   float* __restrict__ pv,
                                                   int*   __restrict__ pi) {
    __shared__ __align__(16) float s_tg[4608];   // blocks [t0-512, t0+4096)
    const int tid  = threadIdx.x;
    const int tile = blockIdx.x & 7;
    const int bf   = blockIdx.x >> 3;
    const int b    = bf / NFRAMES;
    const float* tb = tgt + b * N_SAMP;
    const float4* __restrict__ wc = (const float4*)(wf + bf * 512);
    const int t0 = tile * 4096;
    const int Lb = 4 * tid;

    for (int e4 = tid; e4 < 1152; e4 += 256) {
        int g = t0 - 512 + 4 * e4;
        float4 v;
        if (g >= 0) v = *(const float4*)(tb + g);
        else        v = make_float4(0.f, 0.f, 0.f, 0.f);
        *(float4*)(s_tg + 4 * SW(e4)) = v;
    }
    __syncthreads();

    float4 acc0 = make_float4(0.f, 0.f, 0.f, 0.f);
    float4 acc1 = acc0, acc2 = acc0, acc3 = acc0;
    CONV512(s_tg)

    float best = -3.4e38f;
    int   bidx = 0;
    const int tbase = t0 + 16 * tid;
#define AMX(v, i) if ((v) > best) { best = (v); bidx = (i); }
    AMX(acc0.x, tbase + 0)  AMX(acc0.y, tbase + 1)
    AMX(acc0.z, tbase + 2)  AMX(acc0.w, tbase + 3)
    AMX(acc1.x, tbase + 4)  AMX(acc1.y, tbase + 5)
    AMX(acc1.z, tbase + 6)  AMX(acc1.w, tbase + 7)
    AMX(acc2.x, tbase + 8)  AMX(acc2.y, tbase + 9)
    AMX(acc2.z, tbase + 10) AMX(acc2.w, tbase + 11)
    AMX(acc3.x, tbase + 12) AMX(acc3.y, tbase + 13)
    AMX(acc3.z, tbase + 14) AMX(acc3.w, tbase + 15)
#undef AMX

    float* rv = s_tg;                 // reuse conv buffer for reduction
    int*   ri = (int*)(s_tg + 256);
    __syncthreads();                  // all conv reads of s_tg done
    rv[tid] = best; ri[tid] = bidx;
    __syncthreads();
    for (int s = 128; s > 0; s >>= 1) {
        if (tid < s) {
            float v2 = rv[tid + s]; int i2 = ri[tid + s];
            if (v2 > rv[tid] || (v2 == rv[tid] && i2 < ri[tid])) {
                rv[tid] = v2; ri[tid] = i2;
            }
        }
        __syncthreads();
    }
    if (tid == 0) { pv[blockIdx.x] = rv[0]; pi[blockIdx.x] = ri[0]; }
}

// ---------------------------------------------------------------- kernel C
__global__ __launch_bounds__(256) void k_reduce(const float* __restrict__ pv,
                                                const int* __restrict__ pi,
                                                int* __restrict__ marr) {
    int id = blockIdx.x * 256 + threadIdx.x;
    if (id >= NB * NFRAMES) return;
    float best = -3.4e38f; int bidx = 0x7fffffff;
    for (int t = 0; t < 8; ++t) {
        float v = pv[id * 8 + t]; int i = pi[id * 8 + t];
        if (v > best || (v == best && i < bidx)) { best = v; bidx = i; }
    }
    marr[id] = bidx;
}

// ---------------------------------------------------------------- kernel D
// h[j] = (-1)^(j+m) * (sin(pi*m/32769)/65536) * cot(pi*frac(A_j/D))
//   A_j = j*32769 - m*32768, D = 65536*32769; m==0 -> delta at j=0.
// theta steps by exactly pi/65536 per element -> seed sincos once per quad,
// rotate (2 fmaf) for the other 3. Pole guard |f0|<6.1e-5 -> exact path.
__global__ __launch_bounds__(256, 8) void k_shift_acc(const float* __restrict__ wf,
                                                      const int* __restrict__ marr,
                                                      float* __restrict__ part,
                                                      int nfgm1, int lg, int fpg) {
    __shared__ __align__(16) float s_h[4608];    // blocks [t0-512, t0+4096)
    const int tid   = threadIdx.x;
    const int cid   = blockIdx.x;
    const int fg    = cid & nfgm1;
    const int chunk = (cid >> lg) & 7;
    const int b     = cid >> (lg + 3);
    const int t0    = chunk * 4096;
    const int f0    = fg * fpg;
    const int nf    = (f0 + fpg <= NFRAMES) ? fpg : (NFRAMES - f0);
    const int Lb    = 4 * tid;

    float4 acc0 = make_float4(0.f, 0.f, 0.f, 0.f);
    float4 acc1 = acc0, acc2 = acc0, acc3 = acc0;
    const double invD = 1.0 / 2147549184.0;   // 1/(65536*32769)
    const float  sd   = 4.7936899603827e-05f; // sin(pi/65536); cos == 1.0f in fp32

    for (int u = 0; u < nf; ++u) {
        int bf = b * NFRAMES + f0 + u;
        const float4* __restrict__ wc = (const float4*)(wf + bf * 512);

        int m = marr[bf];
        double md32768 = (double)m * 32768.0;
        double sp = sin((double)m * (M_PI / 32769.0));
        float Cp = (float)(sp * (1.0 / 65536.0));
        if (m & 1) Cp = -Cp;
        float Cn = -Cp;    // odd-j elements

        __syncthreads();   // previous frame's conv reads done before re-staging
        if (m == 0) {
            for (int e4 = tid; e4 < 1152; e4 += 256) {
                int j0 = t0 - 512 + 4 * e4;
                float4 v;
                v.x = (j0 == 0) ? 1.0f : 0.0f;
                v.y = 0.0f; v.z = 0.0f; v.w = 0.0f;
                *(float4*)(s_h + 4 * SW(e4)) = v;
            }
        } else {
            for (int e4 = tid; e4 < 1152; e4 += 256) {
                int j0 = t0 - 512 + 4 * e4;         // always even
                double A0 = (double)j0 * 32769.0 - md32768;   // exact integer
                double rA0 = A0 * invD;
                float f0v = (float)(rA0 - rint(rA0));
                float4 v;
                if (fabsf(f0v) < 6.2e-5f) {
                    // pole within/near this quad: exact per-element path
#pragma unroll
                    for (int k = 0; k < 4; ++k) {
                        double rA = (A0 + (double)k * 32769.0) * invD;
                        float f = (float)(rA - rint(rA));
                        float r;
                        if (f == 0.0f) r = 65535.0f;   // removable 0/0 at A=0
                        else {
                            float s, c;
                            __sincosf((float)M_PI * f, &s, &c);
                            r = c * __builtin_amdgcn_rcpf(s);
                        }
                        ((float*)&v)[k] = ((k & 1) ? Cn : Cp) * r;
                    }
                } else {
                    float s, c;
                    __sincosf((float)M_PI * f0v, &s, &c);
                    v.x = Cp * (c * __builtin_amdgcn_rcpf(s));
                    float s1 = fmaf(c, sd, s);        // rotate by pi/65536
                    float c1 = fmaf(-s, sd, c);
                    v.y = Cn * (c1 * __builtin_amdgcn_rcpf(s1));
                    float s2 = fmaf(c1, sd, s1);
                    float c2 = fmaf(-s1, sd, c1);
                    v.z = Cp * (c2 * __builtin_amdgcn_rcpf(s2));
                    float s3 = fmaf(c2, sd, s2);
                    float c3 = fmaf(-s2, sd, c2);
                    v.w = Cn * (c3 * __builtin_amdgcn_rcpf(s3));
                }
                *(float4*)(s_h + 4 * SW(e4)) = v;
            }
        }
        __syncthreads();

        CONV512(s_h)
    }

    // LDS transpose so global stores are wave-contiguous full lines
    __syncthreads();                  // conv reads of s_h done
    *(float4*)(s_h + 4 * SW(4 * tid + 0)) = acc0;
    *(float4*)(s_h + 4 * SW(4 * tid + 1)) = acc1;
    *(float4*)(s_h + 4 * SW(4 * tid + 2)) = acc2;
    *(float4*)(s_h + 4 * SW(4 * tid + 3)) = acc3;
    __syncthreads();
    float* ob = part + (size_t)fg * (NB * N_SAMP) + b * N_SAMP + t0;
#pragma unroll
    for (int k = 0; k < 4; ++k) {
        float4 v = *(float4*)(s_h + 4 * SW(256 * k + tid));
        *(float4*)(ob + 4 * (256 * k + tid)) = v;   // 4 KB contiguous per wave-store
    }
}

// ---------------------------------------------------------------- kernel E
__global__ __launch_bounds__(256) void k_mse(const float* __restrict__ part,
                                             const float* __restrict__ tgt,
                                             float* __restrict__ out, int nfg) {
    __shared__ float sred[4];
    int e = blockIdx.x * 256 + threadIdx.x;
    float s0 = 0.f, s1 = 0.f, s2 = 0.f, s3 = 0.f;
    for (int g = 0; g + 4 <= nfg; g += 4) {
        s0 += part[(size_t)(g + 0) * (NB * N_SAMP) + e];
        s1 += part[(size_t)(g + 1) * (NB * N_SAMP) + e];
        s2 += part[(size_t)(g + 2) * (NB * N_SAMP) + e];
        s3 += part[(size_t)(g + 3) * (NB * N_SAMP) + e];
    }
    float s = (s0 + s1) + (s2 + s3);
    float d = s - tgt[e];
    float v = d * d;
#pragma unroll
    for (int off = 32; off > 0; off >>= 1) v += __shfl_down(v, off, 64);
    int lane = threadIdx.x & 63, wid = threadIdx.x >> 6;
    if (lane == 0) sred[wid] = v;
    __syncthreads();
    if (threadIdx.x == 0) {
        float sm = sred[0] + sred[1] + sred[2] + sred[3];
        atomicAdd(out, sm * (1.0f / 131072.0f));
    }
}

// ---------------------------------------------------------------- launch
extern "C" void kernel_launch(void* const* d_in, const int* in_sizes, int n_in,
                              void* d_out, int out_size, void* d_ws, size_t ws_size,
                              hipStream_t stream) {
    const float* recon = (const float*)d_in[0];
    const float* tgt   = (const float*)d_in[1];
    float* out = (float*)d_out;
    float* W   = (float*)d_ws;

    float* wf   = W + WS_WF;
    float* pv   = W + WS_PV;
    int*   pi   = (int*)(W + WS_PI);
    int*   marr = (int*)(W + WS_M);
    float* part = W + WS_PART;

    // 64 frame-groups (2 frames each) -> grid 2048 = exactly 8 blocks/CU.
    int nfg = 64, lg = 6, fpg = 2;
    size_t need = ((size_t)WS_PART + (size_t)nfg * NB * N_SAMP) * sizeof(float);
    if (ws_size < need) { nfg = 16; lg = 4; fpg = 8; }

    hipMemsetAsync(out, 0, sizeof(float), stream);

    k_wf<<<(NB * NFRAMES * WINDOW + 255) / 256, 256, 0, stream>>>(recon, wf);
    k_argmax<<<NB * NFRAMES * 8, 256, 0, stream>>>(tgt, wf, pv, pi);
    k_reduce<<<2, 256, 0, stream>>>(pv, pi, marr);
    k_shift_acc<<<NB * 8 * nfg, 256, 0, stream>>>(wf, marr, part, nfg - 1, lg, fpg);
    k_mse<<<512, 256, 0, stream>>>(part, tgt, out, nfg);
}